// Round 8
// baseline (124.704 us; speedup 1.0000x reference)
//
#include <hip/hip_runtime.h>
#include <stdint.h>

// LocallyConnected1d: out[b,c,o] = (1/8) * sum_{i<64,k<8} x[b,i,4o+k] * w[c,i,o,k]
// B=128, CIN=64, COUT=64, OUT_DIM=256, K=8, S=4, L=1028. fp32 in/out.
//
// R11: K2 = flat single-barrier GEMM with EXPLICIT 2-deep register double-
// buffer for B. Ledger: R4 chunked-DMA K2 ~35us, R8 flat-inline K2 ~44us
// (VGPR=52 -> compiler serialized B loads, one L2 round-trip per MFMA pair),
// R10 chunked b16 ~39us. Fix: force load batching by structure - bfr[2][8]
// register arrays (statically indexed, ch-loop unrolled), prefetch chunk
// ch+1's 8x16B coalesced wb loads BEFORE computing chunk ch. No B-LDS, no
// barriers in K-loop, 40KB LDS (A only) -> 4 blk/CU = 16 waves/CU.
// wb layout now XOR-FREE: [q][ch][o_lo][c][i_loc][k] bf16; per-(c-row) the
// 4 quads' granules are 64B-contiguous -> 16 lines per wave load (ideal).
// K1 = R10's split transpose (grid 1024) minus the bank-XOR.

#define CIN_  64
#define COUT_ 64
#define OD_   256
#define K_    8
#define L_    1028

// wb granule layout: [q 128][ch 4][o_lo 2][c 64][i_loc 16] x (8 bf16 = 16B)
#define WB_PER_Q  65536
#define WB_PER_CH 16384

#define ASTR 20   // A_lds row stride in bf16 elems (40 B, non-pow2)

typedef __attribute__((ext_vector_type(8))) short bf16x8;
typedef __attribute__((ext_vector_type(4))) short short4v;
typedef __attribute__((ext_vector_type(4))) float floatx4;

__device__ __forceinline__ unsigned short f32_to_bf16(float f) {
    union { float f; uint32_t u; } v; v.f = f;
    uint32_t u = v.u;
    u += 0x7FFFu + ((u >> 16) & 1u);   // round-to-nearest-even
    return (unsigned short)(u >> 16);
}

// ---------------- K1: w fp32 -> wb bf16 (transpose, no XOR) ----------------
// grid 1024 = 16 c-tiles(4) x 4 i-tiles(16) x 16 o-tiles(16). 256 threads.
__global__ __launch_bounds__(256, 4)
void lc1d_wprep(const float* __restrict__ w, unsigned short* __restrict__ wb) {
    __shared__ __align__(16) unsigned short tile[64 * 136];  // (c,i) rows x (16o x 8k), pad 8

    const int tid = threadIdx.x;
    const int blk = blockIdx.x;
    const int c0  = (blk & 15) * 4;
    const int ch  = (blk >> 4) & 3;
    const int i0  = ch * 16;
    const int ot  = blk >> 6;           // 0..15
    const int o0  = ot * 16;
    const int q0  = ot * 8;

    // read: 64 rows (cL*16+iL) x 512 B contiguous (16 o x 8 k floats)
    #pragma unroll
    for (int it = 0; it < 8; ++it) {
        const int u   = it * 256 + tid;
        const int t   = u & 31;         // float4 within row
        const int row = u >> 5;         // 0..63
        const int iL  = row & 15;
        const int cL  = row >> 4;       // 0..3
        const float4 v = *(const float4*)(w +
            (size_t)((c0 + cL) * CIN_ + (i0 + iL)) * (OD_ * K_) + o0 * K_ + t * 4);
        ushort4 sv = make_ushort4(f32_to_bf16(v.x), f32_to_bf16(v.y),
                                  f32_to_bf16(v.z), f32_to_bf16(v.w));
        *(ushort4*)&tile[row * 136 + t * 4] = sv;
    }
    __syncthreads();

    // write: granule (qL, o_lo, cL, il) -> contiguous 16 B stores in wb order
    #pragma unroll
    for (int it = 0; it < 4; ++it) {
        const int u    = it * 256 + tid;
        const int il   = u & 15;        // i_loc, stored flat (no XOR)
        const int cL   = (u >> 4) & 3;
        const int o_lo = (u >> 6) & 1;
        const int qL   = (u >> 7) & 7;
        const int c    = c0 + cL;
        const int row  = cL * 16 + il;
        const int o_loc = qL * 2 + o_lo;
        const bf16x8 vv = *(const bf16x8*)&tile[row * 136 + o_loc * 8];
        const size_t dst = (size_t)(q0 + qL) * WB_PER_Q + (size_t)ch * WB_PER_CH
                         + ((size_t)((o_lo * 64 + c) * 16 + il) << 3);
        *(bf16x8*)&wb[dst] = vv;
    }
}

// ---------------- K2: GEMM. block = (q, b-eighth), grid 1024 ----------------
__global__ __launch_bounds__(256, 4)
void lc1d_gemm(const float* __restrict__ x,
               const unsigned short* __restrict__ wb,
               float* __restrict__ out) {
    __shared__ __align__(16) unsigned short Al[64 * 16 * ASTR];  // 40 KB, full K

    const int tid = threadIdx.x;
    const int blk = blockIdx.x;
    // XCD swizzle: XCD j hosts q in [16j,16j+16); blk,blk+128 -> same XCD
    const int q   = (blk & 7) * 16 + ((blk >> 3) & 15);
    const int bq  = blk >> 7;           // 0..7
    const int b0  = bq * 16;

    const int wave = tid >> 6;
    const int lane = tid & 63;
    const int quad = lane >> 4;
    const int l16  = lane & 15;
    const int o_lo = wave & 1;          // which o of the pair
    const int nth  = wave >> 1;         // c-half (c = nth*32 + n*16 + l16)

    // per-lane wb base (ushort units): granule (o_lo*64 + nth*32 + n*16 + l16,
    // i_loc = kk*4 + quad); deltas: ch*16384, n*2048, kk*32
    const unsigned short* wq = wb + (size_t)q * WB_PER_Q
                             + ((size_t)(o_lo * 64 + nth * 32 + l16) << 7)
                             + (quad << 3);

    // ---- prefetch B chunk 0 into registers (8 x 16B, wave-coalesced) ----
    bf16x8 bfr[2][8];
    #pragma unroll
    for (int kk = 0; kk < 4; ++kk)
        #pragma unroll
        for (int n = 0; n < 2; ++n)
            bfr[0][kk * 2 + n] = *(const bf16x8*)&wq[n * 2048 + kk * 32];

    // ---- A staging: rows (iL 0..63, bL 0..15) x 12 floats [8q, 8q+12) ----
    #pragma unroll
    for (int it = 0; it < 16; ++it) {
        const int u   = it * 256 + tid;
        const int t   = u & 3;          // float4 within row; t==3 masked
        const int row = u >> 2;         // 0..1023
        const int bL  = row & 15;
        const int iL  = row >> 4;       // 0..63
        if (t < 3) {
            const float4 v = *(const float4*)(x +
                (size_t)((b0 + bL) * CIN_ + iL) * L_ + q * 8 + t * 4);
            ushort4 sv = make_ushort4(f32_to_bf16(v.x), f32_to_bf16(v.y),
                                      f32_to_bf16(v.z), f32_to_bf16(v.w));
            *(ushort4*)&Al[(iL * 16 + bL) * ASTR + t * 4] = sv;
        }
    }
    __syncthreads();   // the kernel's only barrier

    floatx4 acc[2];
    acc[0] = (floatx4){0.f, 0.f, 0.f, 0.f};
    acc[1] = (floatx4){0.f, 0.f, 0.f, 0.f};

    // ---- compute: 4 chunks x {prefetch ch+1 -> regs; 4 kt x 2 MFMA} ----
    #pragma unroll
    for (int ch = 0; ch < 4; ++ch) {
        if (ch < 3) {
            #pragma unroll
            for (int kk = 0; kk < 4; ++kk)
                #pragma unroll
                for (int n = 0; n < 2; ++n)
                    bfr[(ch + 1) & 1][kk * 2 + n] =
                        *(const bf16x8*)&wq[(ch + 1) * 16384 + n * 2048 + kk * 32];
        }
        #pragma unroll
        for (int kk = 0; kk < 4; ++kk) {
            const int kt    = ch * 4 + kk;
            const int abase = ((kt * 4 + quad) * 16 + l16) * ASTR + o_lo * 4;
            const short4v a_lo = *(const short4v*)&Al[abase];
            const short4v a_hi = *(const short4v*)&Al[abase + 4];
            bf16x8 af;
            af[0] = a_lo[0]; af[1] = a_lo[1]; af[2] = a_lo[2]; af[3] = a_lo[3];
            af[4] = a_hi[0]; af[5] = a_hi[1]; af[6] = a_hi[2]; af[7] = a_hi[3];
            #pragma unroll
            for (int n = 0; n < 2; ++n)
                acc[n] = __builtin_amdgcn_mfma_f32_16x16x32_bf16(
                             af, bfr[ch & 1][kk * 2 + n], acc[n], 0, 0, 0);
        }
    }

    // ---- epilogue: D col=l16 (c), row=quad*4+reg (b); scale 1/sqrt(64) ----
    const int o_g = q * 2 + o_lo;
    #pragma unroll
    for (int n = 0; n < 2; ++n) {
        const int c = nth * 32 + n * 16 + l16;
        #pragma unroll
        for (int r = 0; r < 4; ++r) {
            const int b = b0 + quad * 4 + r;
            out[((size_t)b * COUT_ + c) * OD_ + o_g] = acc[n][r] * 0.125f;
        }
    }
}

extern "C" void kernel_launch(void* const* d_in, const int* in_sizes, int n_in,
                              void* d_out, int out_size, void* d_ws, size_t ws_size,
                              hipStream_t stream) {
    const float* x = (const float*)d_in[0];   // (128, 64, 1028)
    const float* w = (const float*)d_in[1];   // (1, 64, 64, 256, 8)
    float* out = (float*)d_out;               // (128, 64, 256)
    unsigned short* wb = (unsigned short*)d_ws; // 16 MiB bf16 workspace

    hipLaunchKernelGGL(lc1d_wprep, dim3(1024), dim3(256), 0, stream, w, wb);
    hipLaunchKernelGGL(lc1d_gemm,  dim3(1024), dim3(256), 0, stream, x, wb, out);
}